// Round 1
// baseline (751.084 us; speedup 1.0000x reference)
//
#include <hip/hip_runtime.h>
#include <hip/hip_bf16.h>

#define L_ 8
#define M_ 128
#define K_ 32
#define D_ 16
#define B_ 2048
#define N_ 1024           // L_*M_
#define SLAB_ 32768       // B_*D_ elements per node slab

// ===========================================================================
// FUSED PER-B PATH
// ---------------------------------------------------------------------------
// Key fact: the recurrence has dependencies only along nodes for a FIXED b.
// Each block owns 2 batch columns (b, b+1) and runs all 8 layers with the
// full node-state resident in LDS (1024 rows x 16 d x 2 b = 128 KiB).
//  - trace gathered from NATIVE layout: line trace[s, b, :] (64 B) is owned
//    by exactly one block -> trace fetched from HBM exactly once (134 MB).
//  - computed-node gathers are LDS reads (no outT buffer, no re-read).
//  - out written native-only, full 64 B lines (134 MB).
//  - W pre-transposed to Wt[n][k][d] so the 4 lanes of an m-group consume a
//    full 64 B line per k (L2 broadcast, no line amplification).
// No transpose pass, no grid sync, 2 kernels total.
// ===========================================================================

__global__ __launch_bounds__(512) void wtrans_kernel(const float* __restrict__ W,
                                                     float* __restrict__ Wt) {
    int n = blockIdx.x;
    int t = threadIdx.x;          // 512 = D_*K_
    int d = t >> 5;               // 0..15
    int k = t & 31;               // 0..31
    Wt[(size_t)n * 512 + k * 16 + d] = W[(size_t)n * 512 + t];
}

// State storage swizzle: ST(row, f, bsl) = row*32 + ((f+row)&15)*2 + bsl.
// Write phase (row = l*128+m, lanes vary m): banks fully spread, 2-way (free).
// Gather phase (random row,f): ~Poisson over 16 banks per bsl half, ~2-4 way.
__global__ __launch_bounds__(512, 2) void fused_kernel(
    const float* __restrict__ x, const float* __restrict__ trace,
    const int* __restrict__ sn, const int* __restrict__ sf,
    const float* __restrict__ Wt, const float* __restrict__ bias,
    float* __restrict__ out)
{
    extern __shared__ float st[];     // 1024*32 floats = 131072 B

    int tid = threadIdx.x;
    int m   = tid >> 2;               // 0..127 : node within layer
    int bsl = (tid >> 1) & 1;         // which of the block's 2 b columns
    int dh  = tid & 1;                // d half: 0 -> d 0..7, 1 -> d 8..15
    int bb  = (blockIdx.x << 1) + bsl;

    const float* xrow = x     + ((size_t)bb << 4);   // x[bb, :]
    const float* trb  = trace + ((size_t)bb << 4);   // + s*SLAB_ later

    for (int l = 0; l < L_; ++l) {
        int n = (l << 7) + m;
        const int* snp = sn + ((size_t)n << 5);
        const int* sfp = sf + ((size_t)n << 5);

        const float4* bp = (const float4*)(bias + ((size_t)n << 4) + (dh << 3));
        float4 bA = bp[0], bB = bp[1];
        float acc[8];
        acc[0] = bA.x; acc[1] = bA.y; acc[2] = bA.z; acc[3] = bA.w;
        acc[4] = bB.x; acc[5] = bB.y; acc[6] = bB.z; acc[7] = bB.w;

        // Wt row for this (n, dh): element k lives at float4 index k*4 (+1).
        const float4* wbase = (const float4*)(Wt + ((size_t)n << 9) + (dh << 3));

        int thr = l << 7;             // s > thr  <=>  source not yet computed
#pragma unroll 8
        for (int k = 0; k < K_; ++k) {
            int s = snp[k];
            int f = sfp[k];
            float g;
            if (s > thr) {                         // stop-grad trace source
                g = trb[((size_t)(s - 1) << 15) + f];
            } else if (s == 0) {                   // x source
                g = xrow[f];
            } else {                               // previously computed node
                int row = s - 1;
                g = st[(row << 5) + (((f + row) & 15) << 1) + bsl];
            }
            float4 w0 = wbase[(k << 2)];
            float4 w1 = wbase[(k << 2) + 1];
            acc[0] = fmaf(g, w0.x, acc[0]); acc[1] = fmaf(g, w0.y, acc[1]);
            acc[2] = fmaf(g, w0.z, acc[2]); acc[3] = fmaf(g, w0.w, acc[3]);
            acc[4] = fmaf(g, w1.x, acc[4]); acc[5] = fmaf(g, w1.y, acc[5]);
            acc[6] = fmaf(g, w1.z, acc[6]); acc[7] = fmaf(g, w1.w, acc[7]);
        }

#pragma unroll
        for (int j = 0; j < 8; ++j) acc[j] = fmaxf(acc[j], 0.0f);

        // Native out: (n, bb, dh*8..dh*8+8). m-group of 4 lanes covers 128 B.
        float4* o4 = (float4*)(out + (((size_t)((n << 11) + bb)) << 4) + (dh << 3));
        o4[0] = make_float4(acc[0], acc[1], acc[2], acc[3]);
        o4[1] = make_float4(acc[4], acc[5], acc[6], acc[7]);

        if (l < L_ - 1) {
            int fb = dh << 3;
#pragma unroll
            for (int j = 0; j < 8; ++j) {
                st[(n << 5) + ((((fb + j) + n) & 15) << 1) + bsl] = acc[j];
            }
            __syncthreads();
        }
    }
}

// ===========================================================================
// FALLBACK PATH (previous verified implementation) — used only if dynamic-LDS
// opt-in fails or workspace is too small.
// ===========================================================================

__global__ __launch_bounds__(256) void transpose_bd(const float* __restrict__ trace,
                                                    const float* __restrict__ x,
                                                    float* __restrict__ traceT,
                                                    float* __restrict__ xT) {
    int blk = blockIdx.x;
    const float* src;
    float* dst;
    int bt;
    if (blk < N_ * 32) {
        int n = blk >> 5;
        src = trace + (size_t)n * SLAB_;
        dst = traceT + (size_t)n * SLAB_;
        bt  = blk & 31;
    } else {
        src = x;
        dst = xT;
        bt  = blk - N_ * 32;
    }
    int b0 = bt * 64;

    __shared__ float lds[D_][65];

    int tid = threadIdx.x;
    const float4* s4 = (const float4*)src;
    int b  = tid >> 2;
    int dq = tid & 3;
    float4 v = s4[(size_t)(b0 + b) * 4 + dq];
    lds[dq * 4 + 0][b] = v.x;
    lds[dq * 4 + 1][b] = v.y;
    lds[dq * 4 + 2][b] = v.z;
    lds[dq * 4 + 3][b] = v.w;
    __syncthreads();

    int d  = tid >> 4;
    int bq = tid & 15;
    float4 w;
    w.x = lds[d][bq * 4 + 0];
    w.y = lds[d][bq * 4 + 1];
    w.z = lds[d][bq * 4 + 2];
    w.w = lds[d][bq * 4 + 3];
    ((float4*)(dst + (size_t)d * B_ + b0))[bq] = w;
}

__global__ __launch_bounds__(256) void layer_kernel(
    int l,
    const float* __restrict__ xbuf, int xfs, int xbs,
    const float* __restrict__ tbuf, int tfs, int tbs,
    const float* __restrict__ obuf, int ofs, int obs,
    const int* __restrict__ sn, const int* __restrict__ sf,
    const float* __restrict__ W, const float* __restrict__ bias,
    float* __restrict__ out, float* __restrict__ outT, int writeT)
{
    int m  = blockIdx.x >> 3;
    int bt = blockIdx.x & 7;
    int n  = l * M_ + m;
    int b  = bt * 256 + threadIdx.x;

    __shared__ float        Wsh[D_][K_];
    __shared__ float        bsh[D_];
    __shared__ const float* colp[K_];
    __shared__ int          colbs[K_];
    __shared__ float        osh[256][17];

    int tid = threadIdx.x;

    if (tid < 128) {
        ((float4*)&Wsh[0][0])[tid] = ((const float4*)(W + (size_t)n * D_ * K_))[tid];
    }
    if (tid < D_) bsh[tid] = bias[(size_t)n * D_ + tid];
    if (tid < K_) {
        int s = sn[(size_t)n * K_ + tid];
        int f = sf[(size_t)n * K_ + tid];
        const float* p;
        int bs;
        if (s == 0) {
            p  = xbuf + (size_t)f * xfs;
            bs = xbs;
        } else {
            int ls = (s - 1) >> 7;
            if (ls >= l) {
                p  = tbuf + (size_t)(s - 1) * SLAB_ + (size_t)f * tfs;
                bs = tbs;
            } else {
                p  = obuf + (size_t)(s - 1) * SLAB_ + (size_t)f * ofs;
                bs = obs;
            }
        }
        colp[tid]  = p;
        colbs[tid] = bs;
    }
    __syncthreads();

    float g[K_];
#pragma unroll
    for (int k = 0; k < K_; ++k) {
        g[k] = colp[k][(size_t)b * colbs[k]];
    }

#pragma unroll
    for (int d = 0; d < D_; ++d) {
        float acc = bsh[d];
#pragma unroll
        for (int k = 0; k < K_; ++k) acc = fmaf(g[k], Wsh[d][k], acc);
        acc = fmaxf(acc, 0.0f);
        osh[tid][d] = acc;
        if (writeT) outT[(size_t)n * SLAB_ + (size_t)d * B_ + b] = acc;
    }
    __syncthreads();

    float4* region4 = (float4*)(out + (size_t)n * SLAB_ + (size_t)(bt * 256) * D_);
#pragma unroll
    for (int j = 0; j < 4; ++j) {
        int i   = j * 256 + tid;
        int row = i >> 2;
        int c0  = (i & 3) * 4;
        float4 w;
        w.x = osh[row][c0 + 0];
        w.y = osh[row][c0 + 1];
        w.z = osh[row][c0 + 2];
        w.w = osh[row][c0 + 3];
        region4[i] = w;
    }
}

extern "C" void kernel_launch(void* const* d_in, const int* in_sizes, int n_in,
                              void* d_out, int out_size, void* d_ws, size_t ws_size,
                              hipStream_t stream) {
    const float* x     = (const float*)d_in[0];
    const float* trace = (const float*)d_in[1];
    const int*   sn    = (const int*)d_in[2];
    const int*   sf    = (const int*)d_in[3];
    const float* W     = (const float*)d_in[4];
    const float* bias  = (const float*)d_in[5];
    float*       out   = (float*)d_out;

    static int use_fused = -1;
    if (use_fused < 0) {
        hipError_t e = hipFuncSetAttribute(
            reinterpret_cast<const void*>(fused_kernel),
            hipFuncAttributeMaxDynamicSharedMemorySize, 131072);
        if (e != hipSuccess) {
            (void)hipGetLastError();   // clear sticky error
            use_fused = 0;
        } else {
            use_fused = 1;
        }
    }

    const size_t wt_bytes = sizeof(float) * (size_t)N_ * D_ * K_;   // 2 MB

    if (use_fused == 1 && ws_size >= wt_bytes) {
        float* Wt = (float*)d_ws;
        wtrans_kernel<<<N_, 512, 0, stream>>>(W, Wt);
        fused_kernel<<<B_ / 2, 512, 131072, stream>>>(x, trace, sn, sf, Wt, bias, out);
        return;
    }

    // ---------------- fallback: previous tiered implementation ----------------
    const size_t xT_elems  = (size_t)D_ * B_;
    const size_t big_elems = (size_t)N_ * SLAB_;
    const size_t needA = sizeof(float) * (xT_elems + 2 * big_elems);
    const size_t needB = sizeof(float) * (xT_elems + 1 * big_elems);

    float* ws = (float*)d_ws;

    if (ws_size >= needA) {
        float* xT     = ws;
        float* traceT = ws + xT_elems;
        float* outT   = traceT + big_elems;

        transpose_bd<<<N_ * 32 + 32, 256, 0, stream>>>(trace, x, traceT, xT);
        for (int l = 0; l < L_; ++l) {
            layer_kernel<<<M_ * 8, 256, 0, stream>>>(
                l,
                xT,     B_, 1,
                traceT, B_, 1,
                outT,   B_, 1,
                sn, sf, W, bias, out, outT, 1);
        }
    } else if (ws_size >= needB) {
        float* xT     = ws;
        float* traceT = ws + xT_elems;

        transpose_bd<<<N_ * 32 + 32, 256, 0, stream>>>(trace, x, traceT, xT);
        for (int l = 0; l < L_; ++l) {
            layer_kernel<<<M_ * 8, 256, 0, stream>>>(
                l,
                xT,     B_, 1,
                traceT, B_, 1,
                out,    1,  D_,
                sn, sf, W, bias, out, nullptr, 0);
        }
    } else {
        for (int l = 0; l < L_; ++l) {
            layer_kernel<<<M_ * 8, 256, 0, stream>>>(
                l,
                x,     1, D_,
                trace, 1, D_,
                out,   1, D_,
                sn, sf, W, bias, out, nullptr, 0);
        }
    }
}

// Round 2
// 610.967 us; speedup vs baseline: 1.2293x; 1.2293x over previous
//
#include <hip/hip_runtime.h>
#include <hip/hip_bf16.h>
#include <stdint.h>

#define L_ 8
#define M_ 128
#define K_ 32
#define D_ 16
#define B_ 2048
#define N_ 1024           // L_*M_
#define SLAB_ 32768       // B_*D_ elements per node slab

// ===========================================================================
// FUSED PER-B PATH (v2: branchless flat gathers, 1024-thread blocks)
// ---------------------------------------------------------------------------
// Each block owns 2 batch columns and runs all 8 layers with the node-state
// resident in LDS (1024 x 16 x 2 = 128 KiB). Thread = (m:128, bsl:2, dq:4),
// each thread computes 4 of the 16 output features for its (node, column).
//
// meta[n][k] (prep kernel) packs the gather source resolved per (n,k):
//   tag0: trace, off = (s-1)*SLAB_ + f      (element offset, bb added later)
//   tag1: x,     off = f                     (x row preloaded in LDS)
//   tag2: state, off = swizzled LDS index    (bsl added later)
// Inner loop: 1 meta dword (L2) -> 2 cndmask -> 1 flat_load. All 32 gathers
// per thread are independent and issued before the FMA phase.
// ===========================================================================

__global__ __launch_bounds__(512) void prep_kernel(const float* __restrict__ W,
                                                   const int* __restrict__ sn,
                                                   const int* __restrict__ sf,
                                                   float* __restrict__ Wt,
                                                   uint32_t* __restrict__ meta) {
    int n = blockIdx.x;
    int t = threadIdx.x;          // 512 = D_*K_
    int d = t >> 5;               // 0..15
    int k = t & 31;               // 0..31
    // W[n][d][k] -> Wt[n][k][d]
    Wt[(size_t)n * 512 + k * 16 + d] = W[(size_t)n * 512 + t];
    if (t < K_) {
        int s = sn[(size_t)n * K_ + t];
        int f = sf[(size_t)n * K_ + t];
        int l = n >> 7;
        uint32_t mk;
        if (s == 0) {
            mk = (1u << 30) | (uint32_t)f;
        } else if (s > (l << 7)) {                 // stop-grad trace source
            mk = (uint32_t)((s - 1) * SLAB_ + f);  // tag 0 (fits in 26 bits)
        } else {                                   // previously computed node
            int r = s - 1;
            mk = (2u << 30) | (uint32_t)((r << 5) + (((f + r) & 15) << 1));
        }
        meta[(size_t)n * K_ + t] = mk;
    }
}

// State swizzle: ST(row, f, bsl) = row*32 + ((f+row)&15)*2 + bsl.
__global__ __launch_bounds__(1024) void fused_kernel(
    const float* __restrict__ x, const float* __restrict__ trace,
    const uint32_t* __restrict__ meta, const float* __restrict__ Wt,
    const float* __restrict__ bias, float* __restrict__ out)
{
    extern __shared__ float st[];     // 1024*32 floats = 131072 B
    __shared__ float xs[2][16];

    int tid = threadIdx.x;
    int m   = tid >> 3;               // 0..127 : node within layer
    int bsl = (tid >> 2) & 1;         // which of the block's 2 b columns
    int dq  = tid & 3;                // d quarter: 4 features
    int bb  = (blockIdx.x << 1) + bsl;

    if (tid < 32) {
        int bs = tid >> 4, f = tid & 15;
        xs[bs][f] = x[(((size_t)(blockIdx.x << 1) + bs) << 4) + f];
    }
    __syncthreads();

    const float* trb = trace + ((size_t)bb << 4);  // trace[.., bb, ..]
    const float* stg = st;                          // generic pointer to LDS
    const float* xsg = &xs[bsl][0];

    for (int l = 0; l < L_; ++l) {
        int n = (l << 7) + m;
        const uint32_t* mp = meta + ((size_t)n << 5);

        // -------- gather phase: 32 independent flat loads ----------------
        float g[K_];
#pragma unroll
        for (int k = 0; k < K_; ++k) {
            uint32_t mk  = mp[k];
            uint32_t tag = mk >> 30;
            uint32_t off = mk & 0x3FFFFFFFu;
            const float* p = (tag == 0) ? (trb + off)
                           : (tag == 1) ? (xsg + off)
                           :              (stg + off + bsl);
            g[k] = *p;
        }

        // -------- FMA phase ----------------------------------------------
        float4 bv = *(const float4*)(bias + ((size_t)n << 4) + (dq << 2));
        float a0 = bv.x, a1 = bv.y, a2 = bv.z, a3 = bv.w;

        const float4* wb = (const float4*)(Wt + ((size_t)n << 9)) + dq;
#pragma unroll
        for (int k = 0; k < K_; ++k) {
            float4 w = wb[k << 2];
            a0 = fmaf(g[k], w.x, a0);
            a1 = fmaf(g[k], w.y, a1);
            a2 = fmaf(g[k], w.z, a2);
            a3 = fmaf(g[k], w.w, a3);
        }
        a0 = fmaxf(a0, 0.0f); a1 = fmaxf(a1, 0.0f);
        a2 = fmaxf(a2, 0.0f); a3 = fmaxf(a3, 0.0f);

        // -------- native out store (64 B line per (n,bb) by 4 dq lanes) --
        float4* o4 = (float4*)(out + ((((size_t)n << 11) + bb) << 4) + (dq << 2));
        *o4 = make_float4(a0, a1, a2, a3);

        // -------- state update -------------------------------------------
        if (l < L_ - 1) {
            int fb = dq << 2;
            st[(n << 5) + ((((fb + 0) + n) & 15) << 1) + bsl] = a0;
            st[(n << 5) + ((((fb + 1) + n) & 15) << 1) + bsl] = a1;
            st[(n << 5) + ((((fb + 2) + n) & 15) << 1) + bsl] = a2;
            st[(n << 5) + ((((fb + 3) + n) & 15) << 1) + bsl] = a3;
            __syncthreads();
        }
    }
}

// ===========================================================================
// FALLBACK PATH (verified tiered implementation)
// ===========================================================================

__global__ __launch_bounds__(256) void transpose_bd(const float* __restrict__ trace,
                                                    const float* __restrict__ x,
                                                    float* __restrict__ traceT,
                                                    float* __restrict__ xT) {
    int blk = blockIdx.x;
    const float* src;
    float* dst;
    int bt;
    if (blk < N_ * 32) {
        int n = blk >> 5;
        src = trace + (size_t)n * SLAB_;
        dst = traceT + (size_t)n * SLAB_;
        bt  = blk & 31;
    } else {
        src = x;
        dst = xT;
        bt  = blk - N_ * 32;
    }
    int b0 = bt * 64;

    __shared__ float lds[D_][65];

    int tid = threadIdx.x;
    const float4* s4 = (const float4*)src;
    int b  = tid >> 2;
    int dq = tid & 3;
    float4 v = s4[(size_t)(b0 + b) * 4 + dq];
    lds[dq * 4 + 0][b] = v.x;
    lds[dq * 4 + 1][b] = v.y;
    lds[dq * 4 + 2][b] = v.z;
    lds[dq * 4 + 3][b] = v.w;
    __syncthreads();

    int d  = tid >> 4;
    int bq = tid & 15;
    float4 w;
    w.x = lds[d][bq * 4 + 0];
    w.y = lds[d][bq * 4 + 1];
    w.z = lds[d][bq * 4 + 2];
    w.w = lds[d][bq * 4 + 3];
    ((float4*)(dst + (size_t)d * B_ + b0))[bq] = w;
}

__global__ __launch_bounds__(256) void layer_kernel(
    int l,
    const float* __restrict__ xbuf, int xfs, int xbs,
    const float* __restrict__ tbuf, int tfs, int tbs,
    const float* __restrict__ obuf, int ofs, int obs,
    const int* __restrict__ sn, const int* __restrict__ sf,
    const float* __restrict__ W, const float* __restrict__ bias,
    float* __restrict__ out, float* __restrict__ outT, int writeT)
{
    int m  = blockIdx.x >> 3;
    int bt = blockIdx.x & 7;
    int n  = l * M_ + m;
    int b  = bt * 256 + threadIdx.x;

    __shared__ float        Wsh[D_][K_];
    __shared__ float        bsh[D_];
    __shared__ const float* colp[K_];
    __shared__ int          colbs[K_];
    __shared__ float        osh[256][17];

    int tid = threadIdx.x;

    if (tid < 128) {
        ((float4*)&Wsh[0][0])[tid] = ((const float4*)(W + (size_t)n * D_ * K_))[tid];
    }
    if (tid < D_) bsh[tid] = bias[(size_t)n * D_ + tid];
    if (tid < K_) {
        int s = sn[(size_t)n * K_ + tid];
        int f = sf[(size_t)n * K_ + tid];
        const float* p;
        int bs;
        if (s == 0) {
            p  = xbuf + (size_t)f * xfs;
            bs = xbs;
        } else {
            int ls = (s - 1) >> 7;
            if (ls >= l) {
                p  = tbuf + (size_t)(s - 1) * SLAB_ + (size_t)f * tfs;
                bs = tbs;
            } else {
                p  = obuf + (size_t)(s - 1) * SLAB_ + (size_t)f * ofs;
                bs = obs;
            }
        }
        colp[tid]  = p;
        colbs[tid] = bs;
    }
    __syncthreads();

    float g[K_];
#pragma unroll
    for (int k = 0; k < K_; ++k) {
        g[k] = colp[k][(size_t)b * colbs[k]];
    }

#pragma unroll
    for (int d = 0; d < D_; ++d) {
        float acc = bsh[d];
#pragma unroll
        for (int k = 0; k < K_; ++k) acc = fmaf(g[k], Wsh[d][k], acc);
        acc = fmaxf(acc, 0.0f);
        osh[tid][d] = acc;
        if (writeT) outT[(size_t)n * SLAB_ + (size_t)d * B_ + b] = acc;
    }
    __syncthreads();

    float4* region4 = (float4*)(out + (size_t)n * SLAB_ + (size_t)(bt * 256) * D_);
#pragma unroll
    for (int j = 0; j < 4; ++j) {
        int i   = j * 256 + tid;
        int row = i >> 2;
        int c0  = (i & 3) * 4;
        float4 w;
        w.x = osh[row][c0 + 0];
        w.y = osh[row][c0 + 1];
        w.z = osh[row][c0 + 2];
        w.w = osh[row][c0 + 3];
        region4[i] = w;
    }
}

extern "C" void kernel_launch(void* const* d_in, const int* in_sizes, int n_in,
                              void* d_out, int out_size, void* d_ws, size_t ws_size,
                              hipStream_t stream) {
    const float* x     = (const float*)d_in[0];
    const float* trace = (const float*)d_in[1];
    const int*   sn    = (const int*)d_in[2];
    const int*   sf    = (const int*)d_in[3];
    const float* W     = (const float*)d_in[4];
    const float* bias  = (const float*)d_in[5];
    float*       out   = (float*)d_out;

    static int use_fused = -1;
    if (use_fused < 0) {
        hipError_t e = hipFuncSetAttribute(
            reinterpret_cast<const void*>(fused_kernel),
            hipFuncAttributeMaxDynamicSharedMemorySize, 131072);
        if (e != hipSuccess) {
            (void)hipGetLastError();   // clear sticky error
            use_fused = 0;
        } else {
            use_fused = 1;
        }
    }

    const size_t wt_elems  = (size_t)N_ * D_ * K_;                  // 524288
    const size_t fused_ws  = sizeof(float) * wt_elems
                           + sizeof(uint32_t) * (size_t)N_ * K_;    // 2 MB + 128 KB

    if (use_fused == 1 && ws_size >= fused_ws) {
        float*    Wt   = (float*)d_ws;
        uint32_t* meta = (uint32_t*)(Wt + wt_elems);
        prep_kernel<<<N_, 512, 0, stream>>>(W, sn, sf, Wt, meta);
        fused_kernel<<<B_ / 2, 1024, 131072, stream>>>(x, trace, meta, Wt, bias, out);
        return;
    }

    // ---------------- fallback: previous tiered implementation ----------------
    const size_t xT_elems  = (size_t)D_ * B_;
    const size_t big_elems = (size_t)N_ * SLAB_;
    const size_t needA = sizeof(float) * (xT_elems + 2 * big_elems);
    const size_t needB = sizeof(float) * (xT_elems + 1 * big_elems);

    float* ws = (float*)d_ws;

    if (ws_size >= needA) {
        float* xT     = ws;
        float* traceT = ws + xT_elems;
        float* outT   = traceT + big_elems;

        transpose_bd<<<N_ * 32 + 32, 256, 0, stream>>>(trace, x, traceT, xT);
        for (int l = 0; l < L_; ++l) {
            layer_kernel<<<M_ * 8, 256, 0, stream>>>(
                l,
                xT,     B_, 1,
                traceT, B_, 1,
                outT,   B_, 1,
                sn, sf, W, bias, out, outT, 1);
        }
    } else if (ws_size >= needB) {
        float* xT     = ws;
        float* traceT = ws + xT_elems;

        transpose_bd<<<N_ * 32 + 32, 256, 0, stream>>>(trace, x, traceT, xT);
        for (int l = 0; l < L_; ++l) {
            layer_kernel<<<M_ * 8, 256, 0, stream>>>(
                l,
                xT,     B_, 1,
                traceT, B_, 1,
                out,    1,  D_,
                sn, sf, W, bias, out, nullptr, 0);
        }
    } else {
        for (int l = 0; l < L_; ++l) {
            layer_kernel<<<M_ * 8, 256, 0, stream>>>(
                l,
                x,     1, D_,
                trace, 1, D_,
                out,   1, D_,
                sn, sf, W, bias, out, nullptr, 0);
        }
    }
}